// Round 4
// baseline (2529.929 us; speedup 1.0000x reference)
//
#include <hip/hip_runtime.h>
#include <hip/hip_bf16.h>

#define L_ 2
#define T_ 512
#define B_ 128
#define F_ 4
#define H_ 256
#define QSIGN_MASK 0x5390

typedef __attribute__((ext_vector_type(8))) short short8;
typedef __attribute__((ext_vector_type(4))) float f32x4;

// layer-1 normalized output sequence (fully rewritten every call)
__device__ float g_inter[T_][B_][F_];

__device__ __forceinline__ unsigned f2bf(float f) {
  unsigned u = __float_as_uint(f);
  return (u + 0x7fff + ((u >> 16) & 1)) >> 16;
}
__device__ __forceinline__ float bfs(unsigned short v) { return __uint_as_float(((unsigned)v) << 16); }
__device__ __forceinline__ float fast_sigmoid(float x) { return 1.f / (1.f + __expf(-x)); }
__device__ __forceinline__ float fast_tanh(float x) {
  float a = fabsf(x), e = __expf(2.f * a);
  return copysignf(1.f - 2.f / (e + 1.f), x);
}

union FragU { short8 v; uint4 u; };

__device__ __forceinline__ short8 negfrag(short8 a) {
  FragU f; f.v = a;
  f.u.x ^= 0x80008000u; f.u.y ^= 0x80008000u;
  f.u.z ^= 0x80008000u; f.u.w ^= 0x80008000u;
  return f.v;
}

// 32 WGs x 4 batch, 512 threads = 8 waves (2/SIMD).
// Wave w = (g = w>>1, uh = w&1): covers gate g, output cols q*64 + uh*32 + [0,32).
// MFMA: PRE[16 x 1024] = H[16 x 256] @ U[256 x 1024], M=batch (rows 0-3 valid).
// Quaternion: acc[q] += sign(a,q) * MFMA(Hslice_a, Comp_{a^q}); B frags (unique
// component blocks) persist in registers; signs via xor on shared A frags.
__launch_bounds__(512)
__global__ void qlstm_mfma(const float* __restrict__ x_in,
                           const float* __restrict__ uhr, const float* __restrict__ uhi,
                           const float* __restrict__ uhj, const float* __restrict__ uhk,
                           const float* __restrict__ wxr, const float* __restrict__ wxi,
                           const float* __restrict__ wxj, const float* __restrict__ wxk,
                           const float* __restrict__ wb,
                           const float* __restrict__ fw, const float* __restrict__ fb,
                           int layer, float* __restrict__ out_final)
{
  __shared__ unsigned short sh_h[16][264];   // h state bf16, padded rows (528 B stride)
  __shared__ float sh_pre[4][256][4];        // pre-activations [b][col][gate]
  __shared__ float sh_x[4][4];

  const int t    = threadIdx.x;
  const int lane = t & 63;
  const int wv   = t >> 6;
  const int sub  = lane & 15;
  const int quad = lane >> 4;
  const int g    = wv >> 1;
  const int uh   = wv & 1;
  const int col  = t & 255;
  const int bg0  = blockIdx.x * 4;

  for (int i = t; i < 16 * 264; i += 512) ((unsigned short*)sh_h)[i] = 0;

  // ---- persistent B fragments: 16 = [d(4)][ks(2)][un(2)], bf16 in registers ----
  FragU Bf[16];
  {
    const float* C[4] = {uhr, uhi, uhj, uhk};
    #pragma unroll
    for (int d = 0; d < 4; ++d)
      #pragma unroll
      for (int ks = 0; ks < 2; ++ks)
        #pragma unroll
        for (int un = 0; un < 2; ++un) {
          const float* src = C[d] + (size_t)((layer * 4 + g) * 64 + ks * 32 + quad * 8) * 64
                             + uh * 32 + un * 16 + sub;
          FragU f;
          #pragma unroll
          for (int j = 0; j < 8; ++j) f.v[j] = (short)f2bf(src[j * 64]);
          Bf[(d * 2 + ks) * 2 + un] = f;
        }
  }
  // ---- phase-B constants: signed-expanded Wx (f32) + bias for this thread's col ----
  float wxf[4][4], wbv[4];
  {
    const float* X[4] = {wxr, wxi, wxj, wxk};
    int q = col >> 6, c = col & 63;
    #pragma unroll
    for (int gg = 0; gg < 4; ++gg) {
      wbv[gg] = wb[gg * 256 + col];
      #pragma unroll
      for (int a = 0; a < 4; ++a) {
        float v = X[a ^ q][(layer * 4 + gg) * 64 + c];
        if ((QSIGN_MASK >> (a * 4 + q)) & 1) v = -v;
        wxf[gg][a] = v;
      }
    }
  }
  // ---- projection constants (per-lane fco rows) ----
  float4 fwr[4];
  #pragma unroll
  for (int cth = 0; cth < 4; ++cth) fwr[cth] = *(const float4*)(fw + (lane + cth * 64) * 4);
  const float fb0 = fb[0], fb1 = fb[1], fb2 = fb[2], fb3 = fb[3];

  float cst0 = 0.f, cst1 = 0.f;
  __syncthreads();

  const char* hbase = (const char*)sh_h + sub * 528 + quad * 16;

  for (int step = 0; step < T_; ++step) {
    // ---- phase A: x loader (wave 7), proj of prev step (layer0, waves 0-3), MFMA ----
    if (t >= 448 && t < 452) {
      int b = t - 448;
      const float* xp = (layer == 0) ? (x_in + (size_t)((bg0 + b) * T_ + step) * F_)
                                     : &g_inter[step][bg0 + b][0];
      *(float4*)&sh_x[b][0] = *(const float4*)xp;
    }
    if (out_final == nullptr && step > 0 && wv < 4) {
      const int b = wv;
      float p0 = 0, p1 = 0, p2 = 0, p3 = 0;
      #pragma unroll
      for (int cth = 0; cth < 4; ++cth) {
        float h = bfs(sh_h[b][lane + cth * 64]);
        p0 += h * fwr[cth].x; p1 += h * fwr[cth].y;
        p2 += h * fwr[cth].z; p3 += h * fwr[cth].w;
      }
      #pragma unroll
      for (int off = 32; off; off >>= 1) {
        p0 += __shfl_down(p0, off, 64); p1 += __shfl_down(p1, off, 64);
        p2 += __shfl_down(p2, off, 64); p3 += __shfl_down(p3, off, 64);
      }
      if (lane == 0) {
        p0 += fb0; p1 += fb1; p2 += fb2; p3 += fb3;
        float inv = 1.f / fmaxf(sqrtf(p0*p0 + p1*p1 + p2*p2 + p3*p3), 1e-12f);
        *(float4*)&g_inter[step - 1][bg0 + b][0] =
            make_float4(p0 * inv, p1 * inv, p2 * inv, p3 * inv);
      }
    }

    f32x4 acc[4][2];
    #pragma unroll
    for (int q = 0; q < 4; ++q) {
      f32x4 z = {0.f, 0.f, 0.f, 0.f};
      acc[q][0] = z; acc[q][1] = z;
    }
    #pragma unroll
    for (int ks = 0; ks < 2; ++ks) {
      short8 Ap[4];
      #pragma unroll
      for (int a = 0; a < 4; ++a)
        Ap[a] = *(const short8*)(hbase + a * 128 + ks * 64);
      #pragma unroll
      for (int d = 0; d < 4; ++d) {
        #pragma unroll
        for (int q = 0; q < 4; ++q) {
          const int a = q ^ d;
          short8 Ae = ((QSIGN_MASK >> (a * 4 + q)) & 1) ? negfrag(Ap[a]) : Ap[a];
          acc[q][0] = __builtin_amdgcn_mfma_f32_16x16x32_bf16(
              Ae, Bf[(d * 2 + ks) * 2 + 0].v, acc[q][0], 0, 0, 0);
          acc[q][1] = __builtin_amdgcn_mfma_f32_16x16x32_bf16(
              Ae, Bf[(d * 2 + ks) * 2 + 1].v, acc[q][1], 0, 0, 0);
        }
      }
    }
    if (quad == 0) {   // C/D rows = quad*4+r -> batch; only rows 0-3 are real
      #pragma unroll
      for (int q = 0; q < 4; ++q)
        #pragma unroll
        for (int un = 0; un < 2; ++un) {
          int cc = q * 64 + uh * 32 + un * 16 + sub;
          #pragma unroll
          for (int r = 0; r < 4; ++r) sh_pre[r][cc][g] = acc[q][un][r];
        }
    }
    __syncthreads();   // barrier 1

    // ---- phase B: thread (b = (t>>8)*2+e, col) -> gates, state, h ----
    #pragma unroll
    for (int e = 0; e < 2; ++e) {
      const int b = (t >> 8) * 2 + e;
      float4 P  = *(const float4*)&sh_pre[b][col][0];
      float4 xv = *(const float4*)&sh_x[b][0];
      float pf = P.x + wbv[0] + xv.x*wxf[0][0] + xv.y*wxf[0][1] + xv.z*wxf[0][2] + xv.w*wxf[0][3];
      float pi = P.y + wbv[1] + xv.x*wxf[1][0] + xv.y*wxf[1][1] + xv.z*wxf[1][2] + xv.w*wxf[1][3];
      float po = P.z + wbv[2] + xv.x*wxf[2][0] + xv.y*wxf[2][1] + xv.z*wxf[2][2] + xv.w*wxf[2][3];
      float pc = P.w + wbv[3] + xv.x*wxf[3][0] + xv.y*wxf[3][1] + xv.z*wxf[3][2] + xv.w*wxf[3][3];
      float fg = fast_sigmoid(pf), ig = fast_sigmoid(pi), og = fast_sigmoid(po);
      float cv = fast_tanh(pc);
      float cs = (e == 0) ? cst0 : cst1;
      cs = ig * cv + fg * cs;
      if (e == 0) cst0 = cs; else cst1 = cs;
      float h = og * fast_tanh(cs);
      sh_h[b][col] = (unsigned short)f2bf(h);
    }
    __syncthreads();   // barrier 2
  }

  // ---- epilogue: projection of final step ----
  if (wv < 4) {
    const int b = wv;
    float p0 = 0, p1 = 0, p2 = 0, p3 = 0;
    #pragma unroll
    for (int cth = 0; cth < 4; ++cth) {
      float h = bfs(sh_h[b][lane + cth * 64]);
      p0 += h * fwr[cth].x; p1 += h * fwr[cth].y;
      p2 += h * fwr[cth].z; p3 += h * fwr[cth].w;
    }
    #pragma unroll
    for (int off = 32; off; off >>= 1) {
      p0 += __shfl_down(p0, off, 64); p1 += __shfl_down(p1, off, 64);
      p2 += __shfl_down(p2, off, 64); p3 += __shfl_down(p3, off, 64);
    }
    if (lane == 0) {
      p0 += fb0; p1 += fb1; p2 += fb2; p3 += fb3;
      float inv = 1.f / fmaxf(sqrtf(p0*p0 + p1*p1 + p2*p2 + p3*p3), 1e-12f);
      float4 v = make_float4(p0 * inv, p1 * inv, p2 * inv, p3 * inv);
      if (out_final) *(float4*)(out_final + (bg0 + b) * F_) = v;
      else           *(float4*)&g_inter[T_ - 1][bg0 + b][0] = v;
    }
  }
}

extern "C" void kernel_launch(void* const* d_in, const int* in_sizes, int n_in,
                              void* d_out, int out_size, void* d_ws, size_t ws_size,
                              hipStream_t stream) {
  const float* x   = (const float*)d_in[0];
  const float* wxr = (const float*)d_in[1];
  const float* wxi = (const float*)d_in[2];
  const float* wxj = (const float*)d_in[3];
  const float* wxk = (const float*)d_in[4];
  const float* wxb = (const float*)d_in[5];
  const float* uhr = (const float*)d_in[6];
  const float* uhi = (const float*)d_in[7];
  const float* uhj = (const float*)d_in[8];
  const float* uhk = (const float*)d_in[9];
  const float* fcw = (const float*)d_in[10];
  const float* fcb = (const float*)d_in[11];
  float* out = (float*)d_out;

  for (int l = 0; l < L_; ++l) {
    qlstm_mfma<<<dim3(B_ / 4), dim3(512), 0, stream>>>(
        x, uhr, uhi, uhj, uhk, wxr, wxi, wxj, wxk,
        wxb + l * 4 * H_, fcw + l * H_ * F_, fcb + l * F_, l,
        (l == L_ - 1) ? out : nullptr);
  }
}

// Round 5
// 1058.718 us; speedup vs baseline: 2.3896x; 2.3896x over previous
//
#include <hip/hip_runtime.h>
#include <hip/hip_bf16.h>

#define L_ 2
#define T_ 512
#define B_ 128
#define F_ 4
#define H_ 256
#define QSIGN_MASK 0x5390

typedef __attribute__((ext_vector_type(8))) short short8;
typedef __attribute__((ext_vector_type(4))) float f32x4;

// layer-0 normalized output sequence + progress flags (rewritten every call)
__device__ float g_inter[T_][B_][F_];
__device__ int   g_prog[32];

__global__ void init_prog_k() { if (threadIdx.x < 32) g_prog[threadIdx.x] = 0; }

__device__ __forceinline__ unsigned f2bf(float f) {
  unsigned u = __float_as_uint(f);
  return (u + 0x7fff + ((u >> 16) & 1)) >> 16;
}
__device__ __forceinline__ float bfs(unsigned short v) { return __uint_as_float(((unsigned)v) << 16); }
__device__ __forceinline__ float fast_sigmoid(float x) { return 1.f / (1.f + __expf(-x)); }
__device__ __forceinline__ float fast_tanh(float x) {
  float a = fabsf(x), e = __expf(2.f * a);
  return copysignf(1.f - 2.f / (e + 1.f), x);
}
__device__ __forceinline__ unsigned long long pack2(float a, float b) {
  return ((unsigned long long)__float_as_uint(b) << 32) | (unsigned long long)__float_as_uint(a);
}
__device__ __forceinline__ float unpack_lo(unsigned long long v) { return __uint_as_float((unsigned)v); }
__device__ __forceinline__ float unpack_hi(unsigned long long v) { return __uint_as_float((unsigned)(v >> 32)); }

union FragU { short8 v; uint4 u; };

// Grid = 64 WGs x 512 threads. blockIdx<32: producer (layer 0, batch group bg);
// blockIdx>=32: consumer (layer 1, same bg). Producer publishes g_inter[t] with
// agent-scope atomics + release flag; consumer prefetches x[t+1] one step ahead.
// MFMA per step: rows = (q,b) 16 valid rows; A = sign-permuted h slices from LDS,
// B = 16 persistent component fragments in registers; 16 MFMAs/wave/step.
__launch_bounds__(512, 2)
__global__ void qlstm_fused(const float* __restrict__ x_in,
                            const float* __restrict__ uhr, const float* __restrict__ uhi,
                            const float* __restrict__ uhj, const float* __restrict__ uhk,
                            const float* __restrict__ wxr, const float* __restrict__ wxi,
                            const float* __restrict__ wxj, const float* __restrict__ wxk,
                            const float* __restrict__ wxb_all,
                            const float* __restrict__ fcw_all, const float* __restrict__ fcb_all,
                            float* __restrict__ out_final)
{
  __shared__ unsigned short sh_h[4][272];   // h state bf16, row stride 544 B
  __shared__ float sh_pre[4][256][4];       // pre-activations [b][col][gate]
  __shared__ float sh_x[2][4][4];           // double-buffered x

  const int t    = threadIdx.x;
  const int role = blockIdx.x >> 5;         // 0 = layer0 producer, 1 = layer1 consumer
  const int bg   = blockIdx.x & 31;
  const int layer = role;
  const int lane = t & 63;
  const int wv   = t >> 6;
  const int sub  = lane & 15;
  const int quad = lane >> 4;
  const int g    = wv >> 1;
  const int uh   = wv & 1;
  const int col  = t & 255;
  const int bg0  = bg * 4;

  const float* wb = wxb_all + layer * 4 * H_;
  const float* fw = fcw_all + layer * H_ * F_;
  const float* fb = fcb_all + layer * F_;

  for (int i = t; i < 4 * 272; i += 512) ((unsigned short*)sh_h)[i] = 0;

  // ---- persistent B fragments [d][ks][un] (raw component blocks, bf16) ----
  FragU Bf[16];
  {
    const float* Cc[4] = {uhr, uhi, uhj, uhk};
    #pragma unroll
    for (int d = 0; d < 4; ++d)
      #pragma unroll
      for (int ks = 0; ks < 2; ++ks)
        #pragma unroll
        for (int un = 0; un < 2; ++un) {
          const float* src = Cc[d] + (size_t)((layer * 4 + g) * 64 + ks * 32 + quad * 8) * 64
                             + uh * 32 + un * 16 + sub;
          FragU f;
          #pragma unroll
          for (int j = 0; j < 8; ++j) f.v[j] = (short)f2bf(src[j * 64]);
          Bf[d * 4 + ks * 2 + un] = f;
        }
  }
  // ---- per-lane sign masks + A-read bases: A rows m = (q=sub>>2, b=sub&3) ----
  unsigned smask[4];
  int abase[4];
  {
    const int ql = sub >> 2, bq = sub & 3;
    #pragma unroll
    for (int d = 0; d < 4; ++d) {
      int a = ql ^ d;
      smask[d] = ((QSIGN_MASK >> (a * 4 + ql)) & 1) ? 0x80008000u : 0u;
      abase[d] = bq * 544 + ((a * 64 + quad * 8) << 1);
    }
  }
  // ---- phase-B constants: signed-expanded Wx + bias for this thread's col ----
  float wxf[4][4], wbv[4];
  {
    const float* X[4] = {wxr, wxi, wxj, wxk};
    int q = col >> 6, c = col & 63;
    #pragma unroll
    for (int gg = 0; gg < 4; ++gg) {
      wbv[gg] = wb[gg * 256 + col];
      #pragma unroll
      for (int a = 0; a < 4; ++a) {
        float v = X[a ^ q][(layer * 4 + gg) * 64 + c];
        if ((QSIGN_MASK >> (a * 4 + q)) & 1) v = -v;
        wxf[gg][a] = v;
      }
    }
  }
  // ---- projection constants ----
  float4 fwr[4];
  #pragma unroll
  for (int cth = 0; cth < 4; ++cth) fwr[cth] = *(const float4*)(fw + (lane + cth * 64) * 4);
  const float fb0 = fb[0], fb1 = fb[1], fb2 = fb[2], fb3 = fb[3];

  // ---- prologue: x[0] ----
  if (t >= 448 && t < 452) {
    int b = t - 448;
    if (role == 0) {
      *(float4*)&sh_x[0][b][0] = *(const float4*)(x_in + (size_t)((bg0 + b) * T_ + 0) * F_);
    } else {
      while (__hip_atomic_load(&g_prog[bg], __ATOMIC_ACQUIRE, __HIP_MEMORY_SCOPE_AGENT) < 1)
        __builtin_amdgcn_s_sleep(2);
      const unsigned long long* sp = (const unsigned long long*)&g_inter[0][bg0 + b][0];
      unsigned long long a0 = __hip_atomic_load(sp + 0, __ATOMIC_RELAXED, __HIP_MEMORY_SCOPE_AGENT);
      unsigned long long a1 = __hip_atomic_load(sp + 1, __ATOMIC_RELAXED, __HIP_MEMORY_SCOPE_AGENT);
      sh_x[0][b][0] = unpack_lo(a0); sh_x[0][b][1] = unpack_hi(a0);
      sh_x[0][b][2] = unpack_lo(a1); sh_x[0][b][3] = unpack_hi(a1);
    }
  }
  float cst0 = 0.f, cst1 = 0.f;
  __syncthreads();

  const char* hbB = (const char*)sh_h;

  for (int step = 0; step < T_; ++step) {
    // ---- phase A: x prefetch (wave 7), producer projection (waves 0-3), MFMA ----
    if (t >= 448 && t < 452 && step + 1 < T_) {
      int b = t - 448;
      if (role == 0) {
        *(float4*)&sh_x[(step + 1) & 1][b][0] =
            *(const float4*)(x_in + (size_t)((bg0 + b) * T_ + step + 1) * F_);
      } else {
        while (__hip_atomic_load(&g_prog[bg], __ATOMIC_ACQUIRE, __HIP_MEMORY_SCOPE_AGENT) < step + 2)
          __builtin_amdgcn_s_sleep(2);
        const unsigned long long* sp = (const unsigned long long*)&g_inter[step + 1][bg0 + b][0];
        unsigned long long a0 = __hip_atomic_load(sp + 0, __ATOMIC_RELAXED, __HIP_MEMORY_SCOPE_AGENT);
        unsigned long long a1 = __hip_atomic_load(sp + 1, __ATOMIC_RELAXED, __HIP_MEMORY_SCOPE_AGENT);
        float* dx = &sh_x[(step + 1) & 1][b][0];
        dx[0] = unpack_lo(a0); dx[1] = unpack_hi(a0);
        dx[2] = unpack_lo(a1); dx[3] = unpack_hi(a1);
      }
    }
    if (role == 0 && step > 0 && wv < 4) {
      const int b = wv;
      float p0 = 0, p1 = 0, p2 = 0, p3 = 0;
      #pragma unroll
      for (int cth = 0; cth < 4; ++cth) {
        float h = bfs(sh_h[b][lane + cth * 64]);
        p0 += h * fwr[cth].x; p1 += h * fwr[cth].y;
        p2 += h * fwr[cth].z; p3 += h * fwr[cth].w;
      }
      #pragma unroll
      for (int off = 32; off; off >>= 1) {
        p0 += __shfl_down(p0, off, 64); p1 += __shfl_down(p1, off, 64);
        p2 += __shfl_down(p2, off, 64); p3 += __shfl_down(p3, off, 64);
      }
      if (lane == 0) {
        p0 += fb0; p1 += fb1; p2 += fb2; p3 += fb3;
        float inv = 1.f / fmaxf(sqrtf(p0*p0 + p1*p1 + p2*p2 + p3*p3), 1e-12f);
        unsigned long long* dst = (unsigned long long*)&g_inter[step - 1][bg0 + b][0];
        __hip_atomic_store(dst + 0, pack2(p0 * inv, p1 * inv), __ATOMIC_RELAXED, __HIP_MEMORY_SCOPE_AGENT);
        __hip_atomic_store(dst + 1, pack2(p2 * inv, p3 * inv), __ATOMIC_RELAXED, __HIP_MEMORY_SCOPE_AGENT);
      }
    }

    // ---- MFMA: rows (q,b); 4-deep chains over d, split by ks ----
    f32x4 acc[4];   // [ks*2+un]
    #pragma unroll
    for (int i = 0; i < 4; ++i) { f32x4 z = {0.f,0.f,0.f,0.f}; acc[i] = z; }
    #pragma unroll
    for (int ks = 0; ks < 2; ++ks) {
      #pragma unroll
      for (int d = 0; d < 4; ++d) {
        FragU A;
        A.u = *(const uint4*)(hbB + abase[d] + ks * 64);
        A.u.x ^= smask[d]; A.u.y ^= smask[d]; A.u.z ^= smask[d]; A.u.w ^= smask[d];
        acc[ks*2+0] = __builtin_amdgcn_mfma_f32_16x16x32_bf16(A.v, Bf[d*4+ks*2+0].v, acc[ks*2+0], 0, 0, 0);
        acc[ks*2+1] = __builtin_amdgcn_mfma_f32_16x16x32_bf16(A.v, Bf[d*4+ks*2+1].v, acc[ks*2+1], 0, 0, 0);
      }
    }
    // C/D: col=lane&15=sub, row=quad*4+reg -> (q=quad, b=reg)
    #pragma unroll
    for (int un = 0; un < 2; ++un) {
      int cc = quad * 64 + uh * 32 + un * 16 + sub;
      #pragma unroll
      for (int r = 0; r < 4; ++r)
        sh_pre[r][cc][g] = acc[0*2+un][r] + acc[1*2+un][r];
    }
    __syncthreads();   // barrier 1
    if (role == 0 && t == 0 && step > 0)
      __hip_atomic_store(&g_prog[bg], step, __ATOMIC_RELEASE, __HIP_MEMORY_SCOPE_AGENT);

    // ---- phase B: thread (b=(t>>8)*2+e, col) -> gates, state, h ----
    #pragma unroll
    for (int e = 0; e < 2; ++e) {
      const int b = (t >> 8) * 2 + e;
      float4 P  = *(const float4*)&sh_pre[b][col][0];
      float4 xv = *(const float4*)&sh_x[step & 1][b][0];
      float pf = P.x + wbv[0] + xv.x*wxf[0][0] + xv.y*wxf[0][1] + xv.z*wxf[0][2] + xv.w*wxf[0][3];
      float pi = P.y + wbv[1] + xv.x*wxf[1][0] + xv.y*wxf[1][1] + xv.z*wxf[1][2] + xv.w*wxf[1][3];
      float po = P.z + wbv[2] + xv.x*wxf[2][0] + xv.y*wxf[2][1] + xv.z*wxf[2][2] + xv.w*wxf[2][3];
      float pc = P.w + wbv[3] + xv.x*wxf[3][0] + xv.y*wxf[3][1] + xv.z*wxf[3][2] + xv.w*wxf[3][3];
      float fg = fast_sigmoid(pf), ig = fast_sigmoid(pi), og = fast_sigmoid(po);
      float cv = fast_tanh(pc);
      float cs = (e == 0) ? cst0 : cst1;
      cs = ig * cv + fg * cs;
      if (e == 0) cst0 = cs; else cst1 = cs;
      float h = og * fast_tanh(cs);
      sh_h[b][col] = (unsigned short)f2bf(h);
    }
    __syncthreads();   // barrier 2
  }

  // ---- epilogue: projection of h[T-1] ----
  if (wv < 4) {
    const int b = wv;
    float p0 = 0, p1 = 0, p2 = 0, p3 = 0;
    #pragma unroll
    for (int cth = 0; cth < 4; ++cth) {
      float h = bfs(sh_h[b][lane + cth * 64]);
      p0 += h * fwr[cth].x; p1 += h * fwr[cth].y;
      p2 += h * fwr[cth].z; p3 += h * fwr[cth].w;
    }
    #pragma unroll
    for (int off = 32; off; off >>= 1) {
      p0 += __shfl_down(p0, off, 64); p1 += __shfl_down(p1, off, 64);
      p2 += __shfl_down(p2, off, 64); p3 += __shfl_down(p3, off, 64);
    }
    if (lane == 0) {
      p0 += fb0; p1 += fb1; p2 += fb2; p3 += fb3;
      float inv = 1.f / fmaxf(sqrtf(p0*p0 + p1*p1 + p2*p2 + p3*p3), 1e-12f);
      if (role == 0) {
        unsigned long long* dst = (unsigned long long*)&g_inter[T_ - 1][bg0 + b][0];
        __hip_atomic_store(dst + 0, pack2(p0 * inv, p1 * inv), __ATOMIC_RELAXED, __HIP_MEMORY_SCOPE_AGENT);
        __hip_atomic_store(dst + 1, pack2(p2 * inv, p3 * inv), __ATOMIC_RELAXED, __HIP_MEMORY_SCOPE_AGENT);
      } else {
        *(float4*)(out_final + (bg0 + b) * F_) =
            make_float4(p0 * inv, p1 * inv, p2 * inv, p3 * inv);
      }
    }
  }
  if (role == 0) {
    __syncthreads();
    if (t == 0)
      __hip_atomic_store(&g_prog[bg], T_, __ATOMIC_RELEASE, __HIP_MEMORY_SCOPE_AGENT);
  }
}

extern "C" void kernel_launch(void* const* d_in, const int* in_sizes, int n_in,
                              void* d_out, int out_size, void* d_ws, size_t ws_size,
                              hipStream_t stream) {
  const float* x   = (const float*)d_in[0];
  const float* wxr = (const float*)d_in[1];
  const float* wxi = (const float*)d_in[2];
  const float* wxj = (const float*)d_in[3];
  const float* wxk = (const float*)d_in[4];
  const float* wxb = (const float*)d_in[5];
  const float* uhr = (const float*)d_in[6];
  const float* uhi = (const float*)d_in[7];
  const float* uhj = (const float*)d_in[8];
  const float* uhk = (const float*)d_in[9];
  const float* fcw = (const float*)d_in[10];
  const float* fcb = (const float*)d_in[11];
  float* out = (float*)d_out;

  init_prog_k<<<dim3(1), dim3(64), 0, stream>>>();
  qlstm_fused<<<dim3(64), dim3(512), 0, stream>>>(
      x, uhr, uhi, uhj, uhk, wxr, wxi, wxj, wxk, wxb, fcw, fcb, out);
}